// Round 5
// baseline (46.466 us; speedup 1.0000x reference)
//
#include <hip/hip_runtime.h>

#define NJ 15
#define FOCALC 575.0f
#define PXC 320.0f
#define PYC 240.0f

constexpr int THREADS = 256;
constexpr int BLOCKS  = 2048;
constexpr int TILE    = 256;   // frames per block-iteration

__device__ __forceinline__ float block_reduce_sum(float val) {
    __shared__ float s[THREADS / 64];
    int lane = threadIdx.x & 63;
    int wid  = threadIdx.x >> 6;
    #pragma unroll
    for (int off = 32; off > 0; off >>= 1)
        val += __shfl_down(val, off, 64);
    if (lane == 0) s[wid] = val;
    __syncthreads();
    if (wid == 0) {
        val = (lane < (THREADS / 64)) ? s[lane] : 0.0f;
        #pragma unroll
        for (int off = (THREADS / 128); off > 0; off >>= 1)
            val += __shfl_down(val, off, 64);
    }
    return val;  // valid in thread 0
}

__global__ __launch_bounds__(THREADS) void proj_partial_kernel(
        const float* __restrict__ pose3d,   // [3][15]
        const float* __restrict__ bone2d,   // [N][2][15] = [N][30]
        const float* __restrict__ R,        // [N][3][3]  = [N][9]
        const float* __restrict__ C,        // [N][3]
        float* __restrict__ partial,        // [BLOCKS]
        int N) {
    __shared__ float sB[TILE * 30];  // 30720 B
    __shared__ float sR[TILE * 9];   //  9216 B
    __shared__ float sC[TILE * 3];   //  3072 B
    __shared__ float p3d[3 * NJ];
    if (threadIdx.x < 3 * NJ) p3d[threadIdx.x] = pose3d[threadIdx.x];

    float acc = 0.0f;
    int nTiles = (N + TILE - 1) / TILE;

    for (int tile = blockIdx.x; tile < nTiles; tile += gridDim.x) {
        int base = tile * TILE;
        int cnt  = min(TILE, N - base);

        __syncthreads();  // LDS from previous iteration fully consumed

        // ---- coalesced staging: global -> LDS as float4 ----
        {   // bone2d tile: cnt*30 floats, tile base offset 16B-aligned
            const float4* src = (const float4*)(bone2d + (long)base * 30);
            int n4 = (cnt * 30) >> 2;
            for (int i = threadIdx.x; i < n4; i += THREADS)
                ((float4*)sB)[i] = src[i];
            for (int i = (n4 << 2) + threadIdx.x; i < cnt * 30; i += THREADS)
                sB[i] = bone2d[(long)base * 30 + i];
        }
        {   // R tile: cnt*9 floats
            const float4* src = (const float4*)(R + (long)base * 9);
            int n4 = (cnt * 9) >> 2;
            for (int i = threadIdx.x; i < n4; i += THREADS)
                ((float4*)sR)[i] = src[i];
            for (int i = (n4 << 2) + threadIdx.x; i < cnt * 9; i += THREADS)
                sR[i] = R[(long)base * 9 + i];
        }
        {   // C tile: cnt*3 floats
            const float4* src = (const float4*)(C + (long)base * 3);
            int n4 = (cnt * 3) >> 2;
            for (int i = threadIdx.x; i < n4; i += THREADS)
                ((float4*)sC)[i] = src[i];
            for (int i = (n4 << 2) + threadIdx.x; i < cnt * 3; i += THREADS)
                sC[i] = C[(long)base * 3 + i];
        }
        __syncthreads();

        // ---- compute: one thread per frame, reads from LDS ----
        int t = threadIdx.x;
        if (t < cnt) {
            const float* Rl = sR + t * 9;   // lane stride 9 floats: gcd(9,32)=1, conflict-free
            float r0 = Rl[0], r1 = Rl[1], r2 = Rl[2];
            float r3 = Rl[3], r4 = Rl[4], r5 = Rl[5];
            float r6 = Rl[6], r7 = Rl[7], r8 = Rl[8];
            const float* Cl = sC + t * 3;   // stride 3: conflict-free
            float c0 = Cl[0], c1 = Cl[1], c2 = Cl[2];
            const float* bl = sB + t * 30;  // stride 30: 2-way (free)

            float fs = 0.0f;
            #pragma unroll
            for (int j = 0; j < NJ; ++j) {
                float x0 = p3d[j] - c0;
                float x1 = p3d[NJ + j] - c1;
                float x2 = p3d[2 * NJ + j] - c2;
                // P_cam[c] = sum_k R[k][c] * X[k]   (einsum 'nkc,nkj->ncj')
                float pc0 = r0 * x0 + r3 * x1 + r6 * x2;
                float pc1 = r1 * x0 + r4 * x1 + r7 * x2;
                float pc2 = r2 * x0 + r5 * x1 + r8 * x2;
                float u = FOCALC * pc0 / pc2 + PXC;
                float v = FOCALC * pc1 / pc2 + PYC;
                float du = u - bl[j];
                float dv = v - bl[NJ + j];
                fs += du * du + dv * dv;
            }
            acc += fs / 30.0f;   // per-frame MSE
        }
    }

    float bsum = block_reduce_sum(acc);
    if (threadIdx.x == 0) partial[blockIdx.x] = bsum;
}

__global__ __launch_bounds__(THREADS) void finalize_kernel(
        const float* __restrict__ partial,
        const float* __restrict__ pose3d,
        float* __restrict__ out,
        int nPartial) {
    float acc = 0.0f;
    for (int i = threadIdx.x; i < nPartial; i += blockDim.x)
        acc += partial[i];
    acc = block_reduce_sum(acc);
    if (threadIdx.x == 0) {
        const int lb[6][2] = {{0,1},{1,2},{2,3},{8,9},{9,10},{10,11}};
        const int rb[6][2] = {{0,4},{4,5},{5,6},{8,12},{12,13},{13,14}};
        float sym = 0.0f;
        #pragma unroll
        for (int bb = 0; bb < 6; ++bb) {
            float ll = 0.0f, lr = 0.0f;
            #pragma unroll
            for (int k = 0; k < 3; ++k) {
                float dl = pose3d[k * NJ + lb[bb][0]] - pose3d[k * NJ + lb[bb][1]];
                float dr = pose3d[k * NJ + rb[bb][0]] - pose3d[k * NJ + rb[bb][1]];
                ll += dl * dl;
                lr += dr * dr;
            }
            float d = ll - lr;
            sym += d * d;
        }
        sym /= 6.0f;
        out[0] = 1.0f * sym + 1.0f * acc;
    }
}

extern "C" void kernel_launch(void* const* d_in, const int* in_sizes, int n_in,
                              void* d_out, int out_size, void* d_ws, size_t ws_size,
                              hipStream_t stream) {
    const float* pose3d = (const float*)d_in[0];
    const float* bone2d = (const float*)d_in[1];
    const float* R      = (const float*)d_in[2];
    const float* C      = (const float*)d_in[3];
    float* out = (float*)d_out;
    float* partial = (float*)d_ws;

    int N = in_sizes[3] / 3;  // C_drone has N*3 elements

    proj_partial_kernel<<<BLOCKS, THREADS, 0, stream>>>(pose3d, bone2d, R, C, partial, N);
    finalize_kernel<<<1, THREADS, 0, stream>>>(partial, pose3d, out, BLOCKS);
}

// Round 6
// 37.332 us; speedup vs baseline: 1.2447x; 1.2447x over previous
//
#include <hip/hip_runtime.h>

#define NJ 15
#define FOCALC 575.0f
#define PXC 320.0f
#define PYC 240.0f

constexpr int THREADS = 256;
constexpr int BLOCKS  = 2048;
constexpr int TILE    = 256;   // frames per block-iteration

// Direct global->LDS async copy, 16 B per lane (1 KB per wave-instruction).
// HW semantics (m104/m173): LDS dest = wave-uniform base + lane*16; global
// src is per-lane. Pass uniform lds base, per-lane global address.
__device__ __forceinline__ void load_lds16(const float* g, float* lds) {
    __builtin_amdgcn_global_load_lds(
        (const __attribute__((address_space(1))) void*)g,
        (__attribute__((address_space(3))) void*)lds,
        16, 0, 0);
}

__device__ __forceinline__ float block_reduce_sum(float val) {
    __shared__ float s[THREADS / 64];
    int lane = threadIdx.x & 63;
    int wid  = threadIdx.x >> 6;
    #pragma unroll
    for (int off = 32; off > 0; off >>= 1)
        val += __shfl_down(val, off, 64);
    if (lane == 0) s[wid] = val;
    __syncthreads();
    if (wid == 0) {
        val = (lane < (THREADS / 64)) ? s[lane] : 0.0f;
        #pragma unroll
        for (int off = (THREADS / 128); off > 0; off >>= 1)
            val += __shfl_down(val, off, 64);
    }
    return val;  // valid in thread 0
}

__global__ __launch_bounds__(THREADS) void proj_partial_kernel(
        const float* __restrict__ pose3d,   // [3][15]
        const float* __restrict__ bone2d,   // [N][30]
        const float* __restrict__ R,        // [N][9]
        const float* __restrict__ C,        // [N][3]
        float* __restrict__ partial,        // [BLOCKS]
        int N) {
    __shared__ float sB[TILE * 30];  // 30720 B = 30 chunks of 1 KB
    __shared__ float sR[TILE * 9];   //  9216 B =  9 chunks
    __shared__ float sC[TILE * 3];   //  3072 B =  3 chunks
    __shared__ float p3d[3 * NJ];
    if (threadIdx.x < 3 * NJ) p3d[threadIdx.x] = pose3d[threadIdx.x];

    const int wid  = threadIdx.x >> 6;   // 4 waves
    const int lane = threadIdx.x & 63;

    float acc = 0.0f;
    const int nTiles = (N + TILE - 1) / TILE;

    for (int tile = blockIdx.x; tile < nTiles; tile += gridDim.x) {
        const int base = tile * TILE;
        const int cnt  = min(TILE, N - base);

        __syncthreads();  // previous tile's LDS fully consumed

        if (cnt == TILE) {
            // ---- async staging: all chunk loads issued back-to-back,
            //      drained once by the barrier's vmcnt(0) ----
            const float* gB = bone2d + (long)base * 30;
            const float* gR = R      + (long)base * 9;
            const float* gC = C      + (long)base * 3;
            #pragma unroll
            for (int c0 = 0; c0 < 32; c0 += 4) {           // 30 chunks
                int c = c0 + wid;
                if (c < 30) load_lds16(gB + c * 256 + lane * 4, sB + c * 256);
            }
            #pragma unroll
            for (int c0 = 0; c0 < 12; c0 += 4) {           // 9 chunks
                int c = c0 + wid;
                if (c < 9) load_lds16(gR + c * 256 + lane * 4, sR + c * 256);
            }
            {                                              // 3 chunks
                int c = wid;
                if (c < 3) load_lds16(gC + c * 256 + lane * 4, sC + c * 256);
            }
        } else {
            // remainder tile (once): coalesced scalar staging
            for (int i = threadIdx.x; i < cnt * 30; i += THREADS)
                sB[i] = bone2d[(long)base * 30 + i];
            for (int i = threadIdx.x; i < cnt * 9; i += THREADS)
                sR[i] = R[(long)base * 9 + i];
            for (int i = threadIdx.x; i < cnt * 3; i += THREADS)
                sC[i] = C[(long)base * 3 + i];
        }
        __syncthreads();

        // ---- compute: one thread per frame, reads from LDS ----
        int t = threadIdx.x;
        if (t < cnt) {
            const float* Rl = sR + t * 9;   // stride 9: conflict-free
            float r0 = Rl[0], r1 = Rl[1], r2 = Rl[2];
            float r3 = Rl[3], r4 = Rl[4], r5 = Rl[5];
            float r6 = Rl[6], r7 = Rl[7], r8 = Rl[8];
            const float* Cl = sC + t * 3;   // stride 3: conflict-free
            float c0 = Cl[0], c1 = Cl[1], c2 = Cl[2];
            const float* bl = sB + t * 30;  // stride 30: 2-way (free)

            float fs = 0.0f;
            #pragma unroll
            for (int j = 0; j < NJ; ++j) {
                float x0 = p3d[j] - c0;
                float x1 = p3d[NJ + j] - c1;
                float x2 = p3d[2 * NJ + j] - c2;
                // P_cam[c] = sum_k R[k][c] * X[k]   (einsum 'nkc,nkj->ncj')
                float pc0 = r0 * x0 + r3 * x1 + r6 * x2;
                float pc1 = r1 * x0 + r4 * x1 + r7 * x2;
                float pc2 = r2 * x0 + r5 * x1 + r8 * x2;
                float u = FOCALC * pc0 / pc2 + PXC;
                float v = FOCALC * pc1 / pc2 + PYC;
                float du = u - bl[j];
                float dv = v - bl[NJ + j];
                fs += du * du + dv * dv;
            }
            acc += fs / 30.0f;   // per-frame MSE
        }
    }

    float bsum = block_reduce_sum(acc);
    if (threadIdx.x == 0) partial[blockIdx.x] = bsum;
}

__global__ __launch_bounds__(THREADS) void finalize_kernel(
        const float* __restrict__ partial,
        const float* __restrict__ pose3d,
        float* __restrict__ out,
        int nPartial) {
    float acc = 0.0f;
    for (int i = threadIdx.x; i < nPartial; i += blockDim.x)
        acc += partial[i];
    acc = block_reduce_sum(acc);
    if (threadIdx.x == 0) {
        const int lb[6][2] = {{0,1},{1,2},{2,3},{8,9},{9,10},{10,11}};
        const int rb[6][2] = {{0,4},{4,5},{5,6},{8,12},{12,13},{13,14}};
        float sym = 0.0f;
        #pragma unroll
        for (int bb = 0; bb < 6; ++bb) {
            float ll = 0.0f, lr = 0.0f;
            #pragma unroll
            for (int k = 0; k < 3; ++k) {
                float dl = pose3d[k * NJ + lb[bb][0]] - pose3d[k * NJ + lb[bb][1]];
                float dr = pose3d[k * NJ + rb[bb][0]] - pose3d[k * NJ + rb[bb][1]];
                ll += dl * dl;
                lr += dr * dr;
            }
            float d = ll - lr;
            sym += d * d;
        }
        sym /= 6.0f;
        out[0] = 1.0f * sym + 1.0f * acc;
    }
}

extern "C" void kernel_launch(void* const* d_in, const int* in_sizes, int n_in,
                              void* d_out, int out_size, void* d_ws, size_t ws_size,
                              hipStream_t stream) {
    const float* pose3d = (const float*)d_in[0];
    const float* bone2d = (const float*)d_in[1];
    const float* R      = (const float*)d_in[2];
    const float* C      = (const float*)d_in[3];
    float* out = (float*)d_out;
    float* partial = (float*)d_ws;

    int N = in_sizes[3] / 3;  // C_drone has N*3 elements

    proj_partial_kernel<<<BLOCKS, THREADS, 0, stream>>>(pose3d, bone2d, R, C, partial, N);
    finalize_kernel<<<1, THREADS, 0, stream>>>(partial, pose3d, out, BLOCKS);
}

// Round 7
// 36.400 us; speedup vs baseline: 1.2765x; 1.0256x over previous
//
#include <hip/hip_runtime.h>

#define NJ 15
#define FOCALC 575.0f
#define PXC 320.0f
#define PYC 240.0f

constexpr int THREADS = 256;
constexpr int BLOCKS  = 2048;
constexpr int TILE    = 128;   // frames per tile (double-buffered)

// Tile region layout (floats): [0,3840) bone | [3840,4992) R | [4992,5376) C
constexpr int OFF_R = TILE * 30;            // 3840
constexpr int OFF_C = TILE * 30 + TILE * 9; // 4992
constexpr int TILE_FLOATS = TILE * 42;      // 5376 floats = 21504 B = 21 KB chunks
constexpr int B_BYTES  = TILE * 30 * 4;     // 15360
constexpr int BR_BYTES = B_BYTES + TILE * 9 * 4; // 19968
constexpr int CHUNKS   = 21;                // 21504 / 1024

// Direct global->LDS async copy, 16 B/lane (1 KB per wave-instruction).
// LDS dest = wave-uniform base + lane*16; global src is per-lane.
__device__ __forceinline__ void load_lds16(const void* g, float* lds) {
    __builtin_amdgcn_global_load_lds(
        (const __attribute__((address_space(1))) void*)g,
        (__attribute__((address_space(3))) void*)lds,
        16, 0, 0);
}

__device__ __forceinline__ float block_reduce_sum(float val) {
    __shared__ float s[THREADS / 64];
    int lane = threadIdx.x & 63;
    int wid  = threadIdx.x >> 6;
    #pragma unroll
    for (int off = 32; off > 0; off >>= 1)
        val += __shfl_down(val, off, 64);
    if (lane == 0) s[wid] = val;
    __syncthreads();
    if (wid == 0) {
        val = (lane < (THREADS / 64)) ? s[lane] : 0.0f;
        #pragma unroll
        for (int off = (THREADS / 128); off > 0; off >>= 1)
            val += __shfl_down(val, off, 64);
    }
    return val;  // valid in thread 0
}

__global__ __launch_bounds__(THREADS) void proj_partial_kernel(
        const float* __restrict__ pose3d,   // [3][15]
        const float* __restrict__ bone2d,   // [N][30]
        const float* __restrict__ R,        // [N][9]
        const float* __restrict__ C,        // [N][3]
        float* __restrict__ partial,        // [BLOCKS]
        int N) {
    __shared__ float sT0[TILE_FLOATS];
    __shared__ float sT1[TILE_FLOATS];
    __shared__ float p3d[3 * NJ];
    if (threadIdx.x < 3 * NJ) p3d[threadIdx.x] = pose3d[threadIdx.x];

    const int wid  = threadIdx.x >> 6;   // 4 waves
    const int lane = threadIdx.x & 63;
    const int nTiles = (N + TILE - 1) / TILE;

    // stage tile -> LDS buffer (async for full tiles; drained by __syncthreads)
    auto stage = [&](float* buf, int tile) {
        const int base = tile * TILE;
        const int cnt  = min(TILE, N - base);
        if (cnt == TILE) {
            const char* gb = (const char*)(bone2d + (long)base * 30);
            const char* gr = (const char*)(R      + (long)base * 9);
            const char* gc = (const char*)(C      + (long)base * 3);
            const int lo = lane * 16;
            #pragma unroll
            for (int k = 0; k < 6; ++k) {
                int c = wid + 4 * k;          // 0..23, wave-uniform guard
                if (c < CHUNKS) {
                    int o = c * 1024 + lo;    // byte offset in combined region
                    const void* g = (o < B_BYTES)  ? (const void*)(gb + o)
                                  : (o < BR_BYTES) ? (const void*)(gr + (o - B_BYTES))
                                                   : (const void*)(gc + (o - BR_BYTES));
                    load_lds16(g, buf + c * 256);
                }
            }
        } else {
            // remainder tile (one block, once): coalesced scalar staging
            for (int i = threadIdx.x; i < cnt * 30; i += THREADS)
                buf[i] = bone2d[(long)base * 30 + i];
            for (int i = threadIdx.x; i < cnt * 9; i += THREADS)
                buf[OFF_R + i] = R[(long)base * 9 + i];
            for (int i = threadIdx.x; i < cnt * 3; i += THREADS)
                buf[OFF_C + i] = C[(long)base * 3 + i];
        }
    };

    float acc = 0.0f;
    const int t0 = blockIdx.x;
    if (t0 < nTiles) stage(sT0, t0);
    __syncthreads();   // drains prologue loads (vmcnt(0)) + p3d writes

    const int f    = threadIdx.x & (TILE - 1);
    const int half = threadIdx.x >> 7;   // wave-uniform: waves 0,1 -> 0; 2,3 -> 1

    int cur = 0;
    for (int t = t0; t < nTiles; t += gridDim.x) {
        float* bufC = cur ? sT1 : sT0;   // compute buffer
        float* bufS = cur ? sT0 : sT1;   // stage buffer
        int nxt = t + gridDim.x;
        if (nxt < nTiles) stage(bufS, nxt);   // issue BEFORE compute: latency hidden

        const int cnt = min(TILE, N - t * TILE);
        if (f < cnt) {
            const float* Rl = bufC + OFF_R + f * 9;   // stride 9: conflict-free
            float r0 = Rl[0], r1 = Rl[1], r2 = Rl[2];
            float r3 = Rl[3], r4 = Rl[4], r5 = Rl[5];
            float r6 = Rl[6], r7 = Rl[7], r8 = Rl[8];
            const float* Cl = bufC + OFF_C + f * 3;   // stride 3: conflict-free
            float c0 = Cl[0], c1 = Cl[1], c2 = Cl[2];
            const float* bl = bufC + f * 30;          // stride 30

            float fs = 0.0f;
            auto term = [&](int j) {
                float x0 = p3d[j] - c0;
                float x1 = p3d[NJ + j] - c1;
                float x2 = p3d[2 * NJ + j] - c2;
                // P_cam[c] = sum_k R[k][c] * X[k]   (einsum 'nkc,nkj->ncj')
                float pc0 = r0 * x0 + r3 * x1 + r6 * x2;
                float pc1 = r1 * x0 + r4 * x1 + r7 * x2;
                float pc2 = r2 * x0 + r5 * x1 + r8 * x2;
                float w = FOCALC / pc2;               // one div, shared by u,v
                float u = pc0 * w + PXC;
                float v = pc1 * w + PYC;
                float du = u - bl[j];
                float dv = v - bl[NJ + j];
                fs += du * du + dv * dv;
            };
            if (half == 0) {
                #pragma unroll
                for (int j = 0; j < 8; ++j) term(j);
            } else {
                #pragma unroll
                for (int j = 8; j < NJ; ++j) term(j);
            }
            acc += fs / 30.0f;   // half-frame contribution; halves sum to mse
        }
        __syncthreads();   // drains next-tile loads (issued pre-compute) + LDS reuse
        cur ^= 1;
    }

    float bsum = block_reduce_sum(acc);
    if (threadIdx.x == 0) partial[blockIdx.x] = bsum;
}

__global__ __launch_bounds__(THREADS) void finalize_kernel(
        const float* __restrict__ partial,
        const float* __restrict__ pose3d,
        float* __restrict__ out,
        int nPartial) {
    float acc = 0.0f;
    for (int i = threadIdx.x; i < nPartial; i += blockDim.x)
        acc += partial[i];
    acc = block_reduce_sum(acc);
    if (threadIdx.x == 0) {
        const int lb[6][2] = {{0,1},{1,2},{2,3},{8,9},{9,10},{10,11}};
        const int rb[6][2] = {{0,4},{4,5},{5,6},{8,12},{12,13},{13,14}};
        float sym = 0.0f;
        #pragma unroll
        for (int bb = 0; bb < 6; ++bb) {
            float ll = 0.0f, lr = 0.0f;
            #pragma unroll
            for (int k = 0; k < 3; ++k) {
                float dl = pose3d[k * NJ + lb[bb][0]] - pose3d[k * NJ + lb[bb][1]];
                float dr = pose3d[k * NJ + rb[bb][0]] - pose3d[k * NJ + rb[bb][1]];
                ll += dl * dl;
                lr += dr * dr;
            }
            float d = ll - lr;
            sym += d * d;
        }
        sym /= 6.0f;
        out[0] = 1.0f * sym + 1.0f * acc;
    }
}

extern "C" void kernel_launch(void* const* d_in, const int* in_sizes, int n_in,
                              void* d_out, int out_size, void* d_ws, size_t ws_size,
                              hipStream_t stream) {
    const float* pose3d = (const float*)d_in[0];
    const float* bone2d = (const float*)d_in[1];
    const float* R      = (const float*)d_in[2];
    const float* C      = (const float*)d_in[3];
    float* out = (float*)d_out;
    float* partial = (float*)d_ws;

    int N = in_sizes[3] / 3;  // C_drone has N*3 elements

    proj_partial_kernel<<<BLOCKS, THREADS, 0, stream>>>(pose3d, bone2d, R, C, partial, N);
    finalize_kernel<<<1, THREADS, 0, stream>>>(partial, pose3d, out, BLOCKS);
}